// Round 1
// baseline (436.504 us; speedup 1.0000x reference)
//
#include <hip/hip_runtime.h>

#define B_ 8192
#define T_ 2048
#define F_ 3
#define H_ 2
#define NG 8      // 4*H
#define L_ 4
#define CHUNKS 16
#define SEG (T_ / CHUNKS)   // 128
#define WARM 96

__device__ __forceinline__ float sigm(float xv) {
    // sigmoid(x) = 1/(1+2^(-x*log2e))
    float e = __builtin_amdgcn_exp2f(-1.442695040888963f * xv);
    return __builtin_amdgcn_rcpf(1.0f + e);
}
__device__ __forceinline__ float tanh_(float xv) {
    // tanh(x) = 2*sigmoid(2x)-1
    float e = __builtin_amdgcn_exp2f(-2.885390081777926f * xv);
    return 2.0f * __builtin_amdgcn_rcpf(1.0f + e) - 1.0f;
}

__global__ __launch_bounds__(256, 2) void lstm_chunk_kernel(
    const float* __restrict__ x,
    const float* __restrict__ w_ih0,
    const float* __restrict__ w_ih_rest,
    const float* __restrict__ w_hh,
    const float* __restrict__ b_ih,
    const float* __restrict__ b_hh,
    const float* __restrict__ w_out,
    const float* __restrict__ b_out,
    float* __restrict__ out)
{
    const int tid   = blockIdx.x * blockDim.x + threadIdx.x;
    const int chunk = tid >> 13;        // tid / B_
    const int e     = tid & (B_ - 1);   // tid % B_

    // ---- load weights (uniform addresses, constant indices -> SGPR-friendly) ----
    float wi0[NG][F_];
    #pragma unroll
    for (int j = 0; j < NG; ++j)
        #pragma unroll
        for (int k = 0; k < F_; ++k)
            wi0[j][k] = w_ih0[j * F_ + k];

    float wir[L_ - 1][NG][H_];
    #pragma unroll
    for (int l = 0; l < L_ - 1; ++l)
        #pragma unroll
        for (int j = 0; j < NG; ++j)
            #pragma unroll
            for (int k = 0; k < H_; ++k)
                wir[l][j][k] = w_ih_rest[(l * NG + j) * H_ + k];

    float whh[L_][NG][H_];
    #pragma unroll
    for (int l = 0; l < L_; ++l)
        #pragma unroll
        for (int j = 0; j < NG; ++j)
            #pragma unroll
            for (int k = 0; k < H_; ++k)
                whh[l][j][k] = w_hh[(l * NG + j) * H_ + k];

    float bb[L_][NG];
    #pragma unroll
    for (int l = 0; l < L_; ++l)
        #pragma unroll
        for (int j = 0; j < NG; ++j)
            bb[l][j] = b_ih[l * NG + j] + b_hh[l * NG + j];

    const float wo0 = w_out[0], wo1 = w_out[1], bo = b_out[0];

    // ---- chunk time range ----
    const int t_start = chunk * SEG;
    const int t0 = (t_start - WARM) > 0 ? (t_start - WARM) : 0;
    const int t1 = t_start + SEG;

    float h[L_][H_], c[L_][H_];
    #pragma unroll
    for (int l = 0; l < L_; ++l) {
        h[l][0] = 0.f; h[l][1] = 0.f;
        c[l][0] = 0.f; c[l][1] = 0.f;
    }

    const float* xp = x + ((long)e * T_ + t0) * F_;
    float* op = out + (long)e * T_ + t_start;

    for (int t = t0; t < t1; ++t) {
        float in0 = xp[0], in1 = xp[1], in2 = xp[2];
        xp += F_;

        #pragma unroll
        for (int l = 0; l < L_; ++l) {
            float g[NG];
            #pragma unroll
            for (int j = 0; j < NG; ++j) {
                float a = bb[l][j];
                if (l == 0) {
                    a += in0 * wi0[j][0] + in1 * wi0[j][1] + in2 * wi0[j][2];
                } else {
                    a += in0 * wir[l - 1][j][0] + in1 * wir[l - 1][j][1];
                }
                a += h[l][0] * whh[l][j][0] + h[l][1] * whh[l][j][1];
                g[j] = a;
            }
            const float si0 = sigm(g[0]), si1 = sigm(g[1]);
            const float sf0 = sigm(g[2]), sf1 = sigm(g[3]);
            const float tg0 = tanh_(g[4]), tg1 = tanh_(g[5]);
            const float so0 = sigm(g[6]), so1 = sigm(g[7]);
            c[l][0] = sf0 * c[l][0] + si0 * tg0;
            c[l][1] = sf1 * c[l][1] + si1 * tg1;
            const float tc0 = tanh_(c[l][0]), tc1 = tanh_(c[l][1]);
            h[l][0] = so0 * tc0;
            h[l][1] = so1 * tc1;
            in0 = h[l][0];
            in1 = h[l][1];
        }

        if (t >= t_start) {          // wave-uniform predicate (B_ multiple of 64)
            *op = in0 * wo0 + in1 * wo1 + bo;
            ++op;
        }
    }
}

extern "C" void kernel_launch(void* const* d_in, const int* in_sizes, int n_in,
                              void* d_out, int out_size, void* d_ws, size_t ws_size,
                              hipStream_t stream) {
    const float* x        = (const float*)d_in[0];
    const float* w_ih0    = (const float*)d_in[1];
    const float* w_ih_rest= (const float*)d_in[2];
    const float* w_hh     = (const float*)d_in[3];
    const float* b_ih     = (const float*)d_in[4];
    const float* b_hh     = (const float*)d_in[5];
    const float* w_out    = (const float*)d_in[6];
    const float* b_out    = (const float*)d_in[7];
    float* out            = (float*)d_out;

    const int total_threads = B_ * CHUNKS;     // 131072
    const int block = 256;
    const int grid = total_threads / block;    // 512
    lstm_chunk_kernel<<<grid, block, 0, stream>>>(
        x, w_ih0, w_ih_rest, w_hh, b_ih, b_hh, w_out, b_out, out);
}